// Round 9
// baseline (281.117 us; speedup 1.0000x reference)
//
#include <hip/hip_runtime.h>
#include <hip/hip_bf16.h>

typedef unsigned short u16;
typedef unsigned int u32;
typedef u16 u16x8 __attribute__((ext_vector_type(8)));
typedef u16 u16x4 __attribute__((ext_vector_type(4)));
typedef __bf16 bf16x8 __attribute__((ext_vector_type(8)));
typedef float f32x4 __attribute__((ext_vector_type(4)));

#define C2 0.0028177637517362567f  // log2(e)/512

__device__ __forceinline__ u16 f2bf(float f) {
  __hip_bfloat16 h = __float2bfloat16(f);
  return __builtin_bit_cast(u16, h);
}
__device__ __forceinline__ float bf2f(u16 v) {
  return __builtin_bit_cast(float, (u32)v << 16);
}

// async global->LDS, 16B per lane. Source data is pre-swizzled so the copy is linear.
__device__ __forceinline__ void gload16(const void* g, void* l) {
  __builtin_amdgcn_global_load_lds((__attribute__((address_space(1))) void*)(g),
                                   (__attribute__((address_space(3))) void*)(l), 16, 0, 0);
}

// ---------------------------------------------------------------------------
// Convert + transpose: src (B,S,L) f32 -> natdst bf16 (B,S,L) swizzled rows i,
//                                      -> trdst bf16 (B,L,S) swizzled rows l.
// Swizzle: element k -> k ^ ((row&7)<<3) within each 64-elem chunk.
// ---------------------------------------------------------------------------
__global__ __launch_bounds__(256) void convert_xpose(const float* __restrict__ src,
                                                     u16* __restrict__ natdst,
                                                     u16* __restrict__ trdst) {
  __shared__ float t[64][65];
  const int b = blockIdx.z;
  const int i0 = blockIdx.y * 64;  // S dim
  const int l0 = blockIdx.x * 64;  // L dim
  const int tid = threadIdx.x;
  const float* sbase = src + ((size_t)b * 1024 + i0) * 1024 + l0;
#pragma unroll
  for (int e = 0; e < 4; ++e) {
    const int idx = e * 256 + tid;
    const int r = idx >> 4, c4 = (idx & 15) * 4;
    float4 v = *(const float4*)(sbase + (size_t)r * 1024 + c4);
    t[r][c4 + 0] = v.x; t[r][c4 + 1] = v.y; t[r][c4 + 2] = v.z; t[r][c4 + 3] = v.w;
  }
  __syncthreads();
  if (natdst) {
    u16* nb = natdst + ((size_t)b * 1024 + i0) * 1024 + l0;
#pragma unroll
    for (int e = 0; e < 2; ++e) {
      const int g = e * 256 + tid;
      const int r = g >> 3, c8 = (g & 7) * 8;
      u16x8 o;
#pragma unroll
      for (int j = 0; j < 8; ++j) o[j] = f2bf(t[r][c8 + j]);
      *(u16x8*)(nb + (size_t)r * 1024 + (c8 ^ ((r & 7) << 3))) = o;
    }
  }
  {
    u16* tb = trdst + ((size_t)b * 1024 + l0) * 1024 + i0;
#pragma unroll
    for (int e = 0; e < 2; ++e) {
      const int g = e * 256 + tid;
      const int lr = g >> 3, i8 = (g & 7) * 8;
      u16x8 o;
#pragma unroll
      for (int j = 0; j < 8; ++j) o[j] = f2bf(t[i8 + j][lr]);
      *(u16x8*)(tb + (size_t)lr * 1024 + (i8 ^ ((lr & 7) << 3))) = o;
    }
  }
}

// W (S,S) f32 -> bf16, row-keyed swizzle (row o over k=i).
__global__ __launch_bounds__(256) void convert_w(const float* __restrict__ w0, const float* __restrict__ w1,
                                                 const float* __restrict__ w2, u16* __restrict__ d0,
                                                 u16* __restrict__ d1, u16* __restrict__ d2) {
  const float* s;
  u16* d;
  if (blockIdx.y == 0) { s = w0; d = d0; }
  else if (blockIdx.y == 1) { s = w1; d = d1; }
  else { s = w2; d = d2; }
  const int g = blockIdx.x * 256 + threadIdx.x;  // 8-elem group
  const int o = g >> 7;
  const int i8 = (g & 127) * 8;
  float4 a = *(const float4*)(s + (size_t)o * 1024 + i8);
  float4 bv = *(const float4*)(s + (size_t)o * 1024 + i8 + 4);
  u16x8 u;
  u[0] = f2bf(a.x); u[1] = f2bf(a.y); u[2] = f2bf(a.z); u[3] = f2bf(a.w);
  u[4] = f2bf(bv.x); u[5] = f2bf(bv.y); u[6] = f2bf(bv.z); u[7] = f2bf(bv.w);
  const int is = (i8 & ~63) | ((i8 & 63) ^ ((o & 7) << 3));
  *(u16x8*)(d + (size_t)o * 1024 + is) = u;
}

// ---------------------------------------------------------------------------
// Merged K/Q projection GEMM, double-buffered (1 barrier per K-tile).
// Grid 1024: bid<512 -> keys (xT x Wk), bid>=512 -> queries (yT x Wq, + Qnat
// natural-layout copy for zmoments). C[l][o] bf16 swizzled, bias per col o.
// Batch-per-XCD swizzle within each half (bijective: 512%8==0).
// ---------------------------------------------------------------------------
__global__ __launch_bounds__(256) void gemm_kq(const u16* __restrict__ xT, const u16* __restrict__ Wk16,
                                               const float* __restrict__ bk, u16* __restrict__ keysT,
                                               const u16* __restrict__ yT, const u16* __restrict__ Wq16,
                                               const float* __restrict__ bq, u16* __restrict__ queriesT,
                                               u16* __restrict__ Qnat) {
  __shared__ u16 Al[2][8192];
  __shared__ u16 Bl[2][8192];
  const int bid = blockIdx.x;  // 1024
  const bool qh = bid >= 512;
  const int lbid = bid & 511;
  const int flat = (lbid & 7) * 64 + (lbid >> 3);  // batch-per-XCD
  const int b = flat >> 6;
  const int m0 = ((flat >> 3) & 7) * 128, n0 = (flat & 7) * 128;
  const int tid = threadIdx.x, lane = tid & 63, w = tid >> 6;
  const int wm = (w >> 1) * 64, wn = (w & 1) * 64;
  const u16* Ab = (qh ? yT : xT) + ((size_t)b * 1024 + m0) * 1024;
  const u16* Bb = (qh ? Wq16 : Wk16) + (size_t)n0 * 1024;
  const float* bias = qh ? bq : bk;
  u16* C = (qh ? queriesT : keysT) + (size_t)b * 1048576;
  f32x4 acc[4][4] = {};
  // prologue: K-tile 0 -> buf 0
#pragma unroll
  for (int p = 0; p < 4; ++p) {
    const int e = p * 2048 + tid * 8, r = e >> 6, c = e & 63;
    gload16(Ab + (size_t)r * 1024 + c, &Al[0][e]);
    gload16(Bb + (size_t)r * 1024 + c, &Bl[0][e]);
  }
  __syncthreads();
  int cur = 0;
  for (int kt = 0; kt < 16; ++kt) {
    if (kt < 15) {
      const int k0 = (kt + 1) * 64;
#pragma unroll
      for (int p = 0; p < 4; ++p) {
        const int e = p * 2048 + tid * 8, r = e >> 6, c = e & 63;
        gload16(Ab + (size_t)r * 1024 + k0 + c, &Al[cur ^ 1][e]);
        gload16(Bb + (size_t)r * 1024 + k0 + c, &Bl[cur ^ 1][e]);
      }
    }
    const u16* Ac = Al[cur];
    const u16* Bc = Bl[cur];
#pragma unroll
    for (int ks = 0; ks < 2; ++ks) {
      const int kk = ks * 32 + (lane >> 4) * 8;
      bf16x8 af[4], bfr[4];
#pragma unroll
      for (int i = 0; i < 4; ++i) {
        const int ra = wm + i * 16 + (lane & 15);
        af[i] = *(const bf16x8*)&Ac[ra * 64 + (kk ^ ((ra & 7) << 3))];
        const int rb = wn + i * 16 + (lane & 15);
        bfr[i] = *(const bf16x8*)&Bc[rb * 64 + (kk ^ ((rb & 7) << 3))];
      }
#pragma unroll
      for (int i = 0; i < 4; ++i)
#pragma unroll
        for (int j = 0; j < 4; ++j)
          acc[i][j] = __builtin_amdgcn_mfma_f32_16x16x32_bf16(af[i], bfr[j], acc[i][j], 0, 0, 0);
    }
    __syncthreads();  // drains this iter's prefetch + closes reads of buf[cur]
    cur ^= 1;
  }
  const int g4 = (lane >> 4) * 4, ln = lane & 15;
#pragma unroll
  for (int i = 0; i < 4; ++i) {
#pragma unroll
    for (int j = 0; j < 4; ++j) {
#pragma unroll
      for (int jj = 0; jj < 4; ++jj) {
        const int r = m0 + wm + i * 16 + g4 + jj;
        const int c = n0 + wn + j * 16 + ln;
        const float v = acc[i][j][jj] + bias[c];
        const int cs = (c & ~63) | ((c & 63) ^ ((r & 7) << 3));
        C[(size_t)r * 1024 + cs] = f2bf(v);
        if (qh) {
          const int ms = (r & ~63) | ((r & 63) ^ ((c & 7) << 3));
          Qnat[((size_t)b * 1024 + c) * 1024 + ms] = f2bf(v);
        }
      }
    }
  }
}

// ---------------------------------------------------------------------------
// Final projection GEMM (f32 out), double-buffered. C[o][l] = Wp[o][:].outT[l][:]
// + bp[o]. A = Wp16 (shared), B = outT per batch.
// ---------------------------------------------------------------------------
__global__ __launch_bounds__(256) void gemm_p(const u16* __restrict__ Wp16, const u16* __restrict__ outT,
                                              const float* __restrict__ bp, float* __restrict__ Cout) {
  __shared__ u16 Al[2][8192];
  __shared__ u16 Bl[2][8192];
  const int bid = blockIdx.x;                      // 512
  const int flat = (bid & 7) * 64 + (bid >> 3);    // batch-per-XCD
  const int b = flat >> 6;
  const int m0 = ((flat >> 3) & 7) * 128, n0 = (flat & 7) * 128;
  const int tid = threadIdx.x, lane = tid & 63, w = tid >> 6;
  const int wm = (w >> 1) * 64, wn = (w & 1) * 64;
  const u16* Ab = Wp16 + (size_t)m0 * 1024;
  const u16* Bb = outT + (size_t)b * 1048576 + (size_t)n0 * 1024;
  float* C = Cout + (size_t)b * 1048576;
  f32x4 acc[4][4] = {};
#pragma unroll
  for (int p = 0; p < 4; ++p) {
    const int e = p * 2048 + tid * 8, r = e >> 6, c = e & 63;
    gload16(Ab + (size_t)r * 1024 + c, &Al[0][e]);
    gload16(Bb + (size_t)r * 1024 + c, &Bl[0][e]);
  }
  __syncthreads();
  int cur = 0;
  for (int kt = 0; kt < 16; ++kt) {
    if (kt < 15) {
      const int k0 = (kt + 1) * 64;
#pragma unroll
      for (int p = 0; p < 4; ++p) {
        const int e = p * 2048 + tid * 8, r = e >> 6, c = e & 63;
        gload16(Ab + (size_t)r * 1024 + k0 + c, &Al[cur ^ 1][e]);
        gload16(Bb + (size_t)r * 1024 + k0 + c, &Bl[cur ^ 1][e]);
      }
    }
    const u16* Ac = Al[cur];
    const u16* Bc = Bl[cur];
#pragma unroll
    for (int ks = 0; ks < 2; ++ks) {
      const int kk = ks * 32 + (lane >> 4) * 8;
      bf16x8 af[4], bfr[4];
#pragma unroll
      for (int i = 0; i < 4; ++i) {
        const int ra = wm + i * 16 + (lane & 15);
        af[i] = *(const bf16x8*)&Ac[ra * 64 + (kk ^ ((ra & 7) << 3))];
        const int rb = wn + i * 16 + (lane & 15);
        bfr[i] = *(const bf16x8*)&Bc[rb * 64 + (kk ^ ((rb & 7) << 3))];
      }
#pragma unroll
      for (int i = 0; i < 4; ++i)
#pragma unroll
        for (int j = 0; j < 4; ++j)
          acc[i][j] = __builtin_amdgcn_mfma_f32_16x16x32_bf16(af[i], bfr[j], acc[i][j], 0, 0, 0);
    }
    __syncthreads();
    cur ^= 1;
  }
  const int g4 = (lane >> 4) * 4, ln = lane & 15;
#pragma unroll
  for (int i = 0; i < 4; ++i) {
#pragma unroll
    for (int j = 0; j < 4; ++j) {
#pragma unroll
      for (int jj = 0; jj < 4; ++jj) {
        const int r = m0 + wm + i * 16 + g4 + jj;
        const int c = n0 + wn + j * 16 + ln;
        C[(size_t)r * 1024 + c] = acc[i][j][jj] + bp[r];
      }
    }
  }
}

// ---------------------------------------------------------------------------
// Taylor-Z stage 1 (4-wave): per bh, M2 = Q Q^T (64x64, contract m=1024) and
// qs[a] = sum_m Q[a][m], from Qnat (d-major). Wave w contracts k-slice
// [w*32,w*32+32) per 128-col chunk; partials summed via LDS.
// ---------------------------------------------------------------------------
__global__ __launch_bounds__(256) void zmoments(const u16* __restrict__ Qnat,
                                                u16* __restrict__ m2bf,
                                                float* __restrict__ qsf) {
  __shared__ u16 Qc[64 * 128];     // 16KB staged chunk (rows a, cols m-local)
  __shared__ float Mp[4 * 4096];   // 64KB per-wave partial M2
  __shared__ float Qp[4 * 64];     // per-wave partial qs
  const int bh = blockIdx.x, b = bh >> 4, h = bh & 15;
  const int tid = threadIdx.x, lane = tid & 63, w = tid >> 6;
  const u16* Qg = Qnat + (size_t)(b * 1024 + h * 64) * 1024;
  f32x4 acc[4][4] = {};
  f32x4 accq[4] = {};
  u16x8 ob;
#pragma unroll
  for (int j = 0; j < 8; ++j) ob[j] = 0x3F80;  // bf16 1.0
  const bf16x8 ones = __builtin_bit_cast(bf16x8, ob);
  const int kk = w * 32 + (lane >> 4) * 8;  // per-wave k-slice of the chunk
  for (int ch = 0; ch < 8; ++ch) {
#pragma unroll
    for (int p = 0; p < 4; ++p) {
      const int e = p * 2048 + tid * 8, r = e >> 7, c = e & 127;
      gload16(Qg + (size_t)r * 1024 + ch * 128 + c, &Qc[e]);
    }
    __syncthreads();
    bf16x8 qf[4];
#pragma unroll
    for (int at = 0; at < 4; ++at) {
      const int a = at * 16 + (lane & 15);
      qf[at] = *(const bf16x8*)&Qc[a * 128 + ((kk & ~63) | ((kk & 63) ^ ((a & 7) << 3)))];
    }
#pragma unroll
    for (int at = 0; at < 4; ++at) {
      accq[at] = __builtin_amdgcn_mfma_f32_16x16x32_bf16(qf[at], ones, accq[at], 0, 0, 0);
#pragma unroll
      for (int bt = 0; bt < 4; ++bt)
        acc[at][bt] = __builtin_amdgcn_mfma_f32_16x16x32_bf16(qf[at], qf[bt], acc[at][bt], 0, 0, 0);
    }
    __syncthreads();  // close Qc reads before next chunk's staging overwrites
  }
  // dump per-wave partials
#pragma unroll
  for (int at = 0; at < 4; ++at)
#pragma unroll
    for (int jj = 0; jj < 4; ++jj) {
      const int a = at * 16 + (lane >> 4) * 4 + jj;
#pragma unroll
      for (int bt = 0; bt < 4; ++bt) {
        const int bc = bt * 16 + (lane & 15);
        Mp[w * 4096 + a * 64 + bc] = acc[at][bt][jj];
      }
      if ((lane & 15) == 0) Qp[w * 64 + a] = accq[at][jj];
    }
  __syncthreads();
  const float im2 = 1.0f / 524288.0f, iqs = 1.0f / 512.0f;
#pragma unroll
  for (int e0 = 0; e0 < 16; ++e0) {
    const int e = tid * 16 + e0;
    const float v = Mp[e] + Mp[4096 + e] + Mp[8192 + e] + Mp[12288 + e];
    const int a = e >> 6, bc = e & 63;
    m2bf[(size_t)bh * 4096 + a * 64 + (bc ^ ((a & 7) << 3))] = f2bf(v * im2);
  }
  if (tid < 64) {
    const float v = Qp[tid] + Qp[64 + tid] + Qp[128 + tid] + Qp[192 + tid];
    qsf[(size_t)bh * 64 + tid] = v * iqs;
  }
}

// ---------------------------------------------------------------------------
// Taylor-Z stage 2: zlog[bh][l] = -log2(1024 + qs'.k_l + k_l^T M2' k_l).
// ---------------------------------------------------------------------------
__global__ __launch_bounds__(256) void zfinal(const u16* __restrict__ m2bf,
                                              const float* __restrict__ qsf,
                                              const u16* __restrict__ keysT,
                                              float* __restrict__ zlog) {
  __shared__ u16 M2[64 * 64];     // 8KB
  __shared__ u16 Kt[256 * 64];    // 32KB, rows = local l
  __shared__ float qls[64];
  const int bid = blockIdx.x;  // 512
  const int bh = bid >> 2, l0 = (bid & 3) * 256;
  const int b = bh >> 4, h = bh & 15;
  const int tid = threadIdx.x, lane = tid & 63, w = tid >> 6;
#pragma unroll
  for (int p = 0; p < 2; ++p) {
    const int e = p * 2048 + tid * 8;
    gload16(m2bf + (size_t)bh * 4096 + e, &M2[e]);
  }
#pragma unroll
  for (int p = 0; p < 8; ++p) {
    const int e = p * 2048 + tid * 8, r = e >> 6, c = e & 63;
    gload16(keysT + ((size_t)b * 1024 + l0 + r) * 1024 + h * 64 + c, &Kt[e]);
  }
  if (tid < 64) qls[tid] = qsf[(size_t)bh * 64 + tid];
  __syncthreads();
  bf16x8 am[4][2], bk[4][2];
#pragma unroll
  for (int ks = 0; ks < 2; ++ks) {
    const int kk = ks * 32 + (lane >> 4) * 8;
#pragma unroll
    for (int t = 0; t < 4; ++t) {
      const int a = t * 16 + (lane & 15);
      am[t][ks] = *(const bf16x8*)&M2[a * 64 + (kk ^ ((a & 7) << 3))];
      const int lr = w * 64 + t * 16 + (lane & 15);
      bk[t][ks] = *(const bf16x8*)&Kt[lr * 64 + (kk ^ ((lr & 7) << 3))];
    }
  }
  f32x4 acc[4][4] = {};
#pragma unroll
  for (int at = 0; at < 4; ++at)
#pragma unroll
    for (int lt = 0; lt < 4; ++lt) {
      acc[at][lt] = __builtin_amdgcn_mfma_f32_16x16x32_bf16(am[at][0], bk[lt][0], acc[at][lt], 0, 0, 0);
      acc[at][lt] = __builtin_amdgcn_mfma_f32_16x16x32_bf16(am[at][1], bk[lt][1], acc[at][lt], 0, 0, 0);
    }
#pragma unroll
  for (int lt = 0; lt < 4; ++lt) {
    const int lr = w * 64 + lt * 16 + (lane & 15);
    float v = 0.f;
#pragma unroll
    for (int at = 0; at < 4; ++at)
#pragma unroll
      for (int jj = 0; jj < 4; ++jj) {
        const int a = at * 16 + (lane >> 4) * 4 + jj;
        const float kv = bf2f(Kt[lr * 64 + (a ^ ((lr & 7) << 3))]);
        v += (qls[a] + acc[at][lt][jj]) * kv;
      }
    v += __shfl_xor(v, 16);
    v += __shfl_xor(v, 32);
    const float Z = 1024.0f + v;
    if (lane < 16)
      zlog[(size_t)bh * 1024 + l0 + w * 64 + lt * 16 + lane] = -__builtin_amdgcn_logf(Z);
  }
}

// ---------------------------------------------------------------------------
// Pass B: out^T[m][dd] = sum_l E^T[m][l] * xs[dd][l],
//   E[l][m] = exp2(s[l][m]*C2 + zlog[l]). Recomputes s per l-chunk.
// Q frags hoisted to regs; K/X double-buffered; El WAVE-PRIVATE (no barrier
// between E-write and PV). One barrier per tile. T5 setprio re-added (safe:
// the R6 failure was the zmoments single-wave race, signature = Z-scale).
// ---------------------------------------------------------------------------
__global__ __launch_bounds__(256) void pass_b(const u16* __restrict__ keysT,
                                              const u16* __restrict__ queriesT,
                                              const u16* __restrict__ xb,
                                              const float* __restrict__ zlog,
                                              u16* __restrict__ outT) {
  __shared__ u16 KX[2][2][4096];  // [buf][0=K,1=X][64x64]
  __shared__ u16 El[128 * 64];    // XOR-swizzled; doubles as Q staging scratch
  __shared__ float Zl[2][64];
  const int bid = blockIdx.x;                      // 1024
  const int flat = (bid & 7) * 128 + (bid >> 3);   // 16 bh per XCD
  const int bh = flat >> 3;
  const int m0 = (flat & 7) * 128;
  const int b = bh >> 4, h = bh & 15;
  const int tid = threadIdx.x, lane = tid & 63, w = tid >> 6;
  const u16* Qg = queriesT + ((size_t)b * 1024 + m0) * 1024 + h * 64;
  const u16* Kg = keysT + (size_t)b * 1024 * 1024 + h * 64;
  const u16* Xg = xb + (size_t)(b * 1024 + h * 64) * 1024;
#pragma unroll
  for (int p = 0; p < 4; ++p) {
    const int e = p * 2048 + tid * 8, r = e >> 6, c = e & 63;
    gload16(Qg + (size_t)r * 1024 + c, &El[e]);
  }
#pragma unroll
  for (int p = 0; p < 2; ++p) {
    const int e = p * 2048 + tid * 8, r = e >> 6, c = e & 63;
    gload16(Kg + (size_t)r * 1024 + c, &KX[0][0][e]);
    gload16(Xg + (size_t)r * 1024 + c, &KX[0][1][e]);
  }
  if (tid < 64) Zl[0][tid] = zlog[(size_t)bh * 1024 + tid];
  __syncthreads();
  bf16x8 bq[2][2];  // loop-invariant Q fragments (wave-private rows of El scratch)
#pragma unroll
  for (int nf = 0; nf < 2; ++nf)
#pragma unroll
    for (int ks = 0; ks < 2; ++ks) {
      const int rb = w * 32 + nf * 16 + (lane & 15);
      const int kk = ks * 32 + (lane >> 4) * 8;
      bq[nf][ks] = *(const bf16x8*)&El[rb * 64 + (kk ^ ((rb & 7) << 3))];
    }
  // no barrier needed: iter-0 E-writes are by the same wave that read this band
  f32x4 acc[2][4] = {};
  int cur = 0;
  for (int lt = 0; lt < 16; ++lt) {
    if (lt < 15) {
      const int l1 = (lt + 1) * 64;
#pragma unroll
      for (int p = 0; p < 2; ++p) {
        const int e = p * 2048 + tid * 8, r = e >> 6, c = e & 63;
        gload16(Kg + (size_t)(l1 + r) * 1024 + c, &KX[cur ^ 1][0][e]);
        gload16(Xg + (size_t)r * 1024 + l1 + c, &KX[cur ^ 1][1][e]);
      }
      if (tid < 64) Zl[cur ^ 1][tid] = zlog[(size_t)bh * 1024 + l1 + tid];
    }
    const u16* Kl = KX[cur][0];
    const u16* Xl = KX[cur][1];
    // scores sub-tile (64 l x 128 m) + E^T build (wave-private El band)
#pragma unroll
    for (int lf = 0; lf < 4; ++lf) {
      bf16x8 ak[2];
#pragma unroll
      for (int ks = 0; ks < 2; ++ks) {
        const int ra = lf * 16 + (lane & 15);
        const int kk = ks * 32 + (lane >> 4) * 8;
        ak[ks] = *(const bf16x8*)&Kl[ra * 64 + (kk ^ ((ra & 7) << 3))];
      }
      const int lb = lf * 16 + (lane >> 4) * 4;
#pragma unroll
      for (int nf = 0; nf < 2; ++nf) {
        f32x4 s = {0.f, 0.f, 0.f, 0.f};
        __builtin_amdgcn_s_setprio(1);
        s = __builtin_amdgcn_mfma_f32_16x16x32_bf16(ak[0], bq[nf][0], s, 0, 0, 0);
        s = __builtin_amdgcn_mfma_f32_16x16x32_bf16(ak[1], bq[nf][1], s, 0, 0, 0);
        __builtin_amdgcn_s_setprio(0);
        const int m = w * 32 + nf * 16 + (lane & 15);
        u16x4 ev;
#pragma unroll
        for (int jj = 0; jj < 4; ++jj)
          ev[jj] = f2bf(__builtin_amdgcn_exp2f(fmaf(s[jj], C2, Zl[cur][lb + jj])));
        *(u16x4*)&El[m * 64 + (lb ^ ((m & 7) << 3))] = ev;
      }
    }
    // PV: out^T[m][dd] += E^T[m][l] * xs[dd][l]
    bf16x8 ae[2][2];
#pragma unroll
    for (int mf = 0; mf < 2; ++mf)
#pragma unroll
      for (int ks = 0; ks < 2; ++ks) {
        const int ra = w * 32 + mf * 16 + (lane & 15);
        const int kk = ks * 32 + (lane >> 4) * 8;
        ae[mf][ks] = *(const bf16x8*)&El[ra * 64 + (kk ^ ((ra & 7) << 3))];
      }
#pragma unroll
    for (int df = 0; df < 4; ++df) {
      bf16x8 bx[2];
#pragma unroll
      for (int ks = 0; ks < 2; ++ks) {
        const int rb = df * 16 + (lane & 15);
        const int kk = ks * 32 + (lane >> 4) * 8;
        bx[ks] = *(const bf16x8*)&Xl[rb * 64 + (kk ^ ((rb & 7) << 3))];
      }
      __builtin_amdgcn_s_setprio(1);
#pragma unroll
      for (int mf = 0; mf < 2; ++mf) {
        acc[mf][df] = __builtin_amdgcn_mfma_f32_16x16x32_bf16(ae[mf][0], bx[0], acc[mf][df], 0, 0, 0);
        acc[mf][df] = __builtin_amdgcn_mfma_f32_16x16x32_bf16(ae[mf][1], bx[1], acc[mf][df], 0, 0, 0);
      }
      __builtin_amdgcn_s_setprio(0);
    }
    __syncthreads();  // drains this iter's prefetch + closes reads of KX[cur]
    cur ^= 1;
  }
  u16* Og = outT + ((size_t)b * 1024 + m0) * 1024 + h * 64;
#pragma unroll
  for (int mf = 0; mf < 2; ++mf)
#pragma unroll
    for (int df = 0; df < 4; ++df)
#pragma unroll
      for (int jj = 0; jj < 4; ++jj) {
        const int m = w * 32 + mf * 16 + (lane >> 4) * 4 + jj;
        const int dd = df * 16 + (lane & 15);
        Og[(size_t)m * 1024 + (dd ^ ((m & 7) << 3))] = f2bf(acc[mf][df][jj]);
      }
}

// ---------------------------------------------------------------------------
extern "C" void kernel_launch(void* const* d_in, const int* in_sizes, int n_in,
                              void* d_out, int out_size, void* d_ws, size_t ws_size,
                              hipStream_t stream) {
  (void)in_sizes; (void)n_in; (void)out_size; (void)ws_size;
  const float* x  = (const float*)d_in[0];
  const float* y  = (const float*)d_in[1];
  const float* Wk = (const float*)d_in[2];
  const float* bk = (const float*)d_in[3];
  const float* Wq = (const float*)d_in[4];
  const float* bq = (const float*)d_in[5];
  const float* Wp = (const float*)d_in[6];
  const float* bp = (const float*)d_in[7];
  float* out = (float*)d_out;

  char* ws = (char*)d_ws;
  size_t off = 0;
  auto wsalloc = [&](size_t bytes) -> void* {
    void* p = ws + off;
    off += (bytes + 255) & ~(size_t)255;
    return p;
  };
  const size_t T16 = (size_t)8 * 1024 * 1024 * 2;  // 16 MB bf16 tensor
  u16* xb       = (u16*)wsalloc(T16);
  u16* xT       = (u16*)wsalloc(T16);
  u16* yT       = (u16*)wsalloc(T16);
  u16* Wk16     = (u16*)wsalloc((size_t)1024 * 1024 * 2);
  u16* Wq16     = (u16*)wsalloc((size_t)1024 * 1024 * 2);
  u16* Wp16     = (u16*)wsalloc((size_t)1024 * 1024 * 2);
  u16* keysT    = (u16*)wsalloc(T16);
  u16* queriesT = (u16*)wsalloc(T16);
  u16* m2bf     = (u16*)wsalloc((size_t)128 * 4096 * 2);
  float* qsf    = (float*)wsalloc((size_t)128 * 64 * 4);
  float* zlog   = (float*)wsalloc((size_t)128 * 1024 * 4);
  // Qnat gets its OWN buffer (total ~103.6MB = known-safe R1/R3 size): the
  // K-half staging of gemm_kq reads xT concurrently (cross-block, unordered)
  // with the Q-half epilogue writes, so aliasing Qnat onto xT would race.
  // outT aliases yT: yT's last reader = Q-half staging of gemm_kq; outT first
  // written by pass_b, 3 dispatches later -- stream-ordered, safe.
  u16* Qnat = (u16*)wsalloc(T16);
  u16* outT = yT;

  const dim3 blk(256);
  convert_xpose<<<dim3(16, 16, 8), blk, 0, stream>>>(x, xb, xT);
  convert_xpose<<<dim3(16, 16, 8), blk, 0, stream>>>(y, nullptr, yT);
  convert_w<<<dim3(512, 3), blk, 0, stream>>>(Wk, Wq, Wp, Wk16, Wq16, Wp16);
  // merged K/Q projections (dbuf, 1 barrier/K-tile)
  gemm_kq<<<dim3(1024), blk, 0, stream>>>(xT, Wk16, bk, keysT, yT, Wq16, bq, queriesT, Qnat);
  zmoments<<<dim3(128), blk, 0, stream>>>(Qnat, m2bf, qsf);
  zfinal<<<dim3(512), blk, 0, stream>>>(m2bf, qsf, keysT, zlog);
  pass_b<<<dim3(1024), blk, 0, stream>>>(keysT, queriesT, xb, zlog, outT);
  // out[b][o][l] = sum_i Wp[o][i] * outT[b][l][i] + bp[o]
  gemm_p<<<dim3(512), blk, 0, stream>>>(Wp16, outT, bp, out);
}